// Round 2
// baseline (5021.095 us; speedup 1.0000x reference)
//
#include <hip/hip_runtime.h>
#include <cstdint>
#include <cstddef>

// Problem constants: B=4, T=2048, C=1024, H=16, d=64
#define T_SEQ 2048
#define CEMB  1024
#define NHEAD 16
#define DHEAD 64

// ---------------------------------------------------------------------------
// GEMM with bias: C[M][N] = A[M][K] @ B[K][N] + bias[N]
// 128x128 tile, BK=16, 256 threads, 8x8 micro-tile per thread (split 4+4).
// fp32 vector FMA (no fp32 MFMA on CDNA4).
// ---------------------------------------------------------------------------
__global__ __launch_bounds__(256) void gemm_bias_kernel(
    const float* __restrict__ A, const float* __restrict__ B,
    const float* __restrict__ bias, float* __restrict__ C,
    int M, int N, int K)
{
    __shared__ float As[16][128];   // [k][m]
    __shared__ float Bs[16][128];   // [k][n]

    const int tid = threadIdx.x;
    const int tx  = tid & 15;   // 0..15 -> output cols
    const int ty  = tid >> 4;   // 0..15 -> output rows

    const int row0 = blockIdx.y * 128;
    const int col0 = blockIdx.x * 128;

    float acc[2][2][4][4];
    #pragma unroll
    for (int a = 0; a < 2; ++a)
        #pragma unroll
        for (int b = 0; b < 2; ++b)
            #pragma unroll
            for (int i = 0; i < 4; ++i)
                #pragma unroll
                for (int j = 0; j < 4; ++j)
                    acc[a][b][i][j] = 0.f;

    const float* Ab = A + (size_t)row0 * K;
    const float* Bb = B + col0;

    for (int kt = 0; kt < K; kt += 16) {
        __syncthreads();
        // Load A tile (transpose to [k][m]): 512 float4 slots
        #pragma unroll
        for (int i = 0; i < 2; ++i) {
            int s  = tid + i * 256;
            int mm = s >> 2;           // 0..127
            int kq = s & 3;            // float4 index along k
            float4 f = *(const float4*)(Ab + (size_t)mm * K + kt + kq * 4);
            As[kq * 4 + 0][mm] = f.x;
            As[kq * 4 + 1][mm] = f.y;
            As[kq * 4 + 2][mm] = f.z;
            As[kq * 4 + 3][mm] = f.w;
        }
        // Load B tile ([k][n], direct): 512 float4 slots
        #pragma unroll
        for (int i = 0; i < 2; ++i) {
            int s  = tid + i * 256;
            int kk = s >> 5;           // 0..15
            int nq = s & 31;           // 0..31
            float4 f = *(const float4*)(Bb + (size_t)(kt + kk) * N + nq * 4);
            *(float4*)&Bs[kk][nq * 4] = f;
        }
        __syncthreads();

        #pragma unroll
        for (int k = 0; k < 16; ++k) {
            float4 a0 = *(const float4*)&As[k][ty * 4];
            float4 a1 = *(const float4*)&As[k][64 + ty * 4];
            float4 b0 = *(const float4*)&Bs[k][tx * 4];
            float4 b1 = *(const float4*)&Bs[k][64 + tx * 4];
            float av[2][4] = {{a0.x, a0.y, a0.z, a0.w}, {a1.x, a1.y, a1.z, a1.w}};
            float bv[2][4] = {{b0.x, b0.y, b0.z, b0.w}, {b1.x, b1.y, b1.z, b1.w}};
            #pragma unroll
            for (int ri = 0; ri < 2; ++ri)
                #pragma unroll
                for (int ci = 0; ci < 2; ++ci)
                    #pragma unroll
                    for (int i = 0; i < 4; ++i)
                        #pragma unroll
                        for (int j = 0; j < 4; ++j)
                            acc[ri][ci][i][j] += av[ri][i] * bv[ci][j];
        }
    }

    // Epilogue: add bias, store float4
    #pragma unroll
    for (int ri = 0; ri < 2; ++ri) {
        #pragma unroll
        for (int i = 0; i < 4; ++i) {
            int row = row0 + ri * 64 + ty * 4 + i;
            #pragma unroll
            for (int ci = 0; ci < 2; ++ci) {
                int col = col0 + ci * 64 + tx * 4;
                float4 bv = *(const float4*)(bias + col);
                float4 r;
                r.x = acc[ri][ci][i][0] + bv.x;
                r.y = acc[ri][ci][i][1] + bv.y;
                r.z = acc[ri][ci][i][2] + bv.z;
                r.w = acc[ri][ci][i][3] + bv.w;
                *(float4*)(C + (size_t)row * N + col) = r;
            }
        }
    }
}

// ---------------------------------------------------------------------------
// Causal flash attention, fp32. ONE WAVE (64 threads) per 64 q-rows.
// Grid: 2048 blocks (1-D), decomposed so consecutive block-groups alternate
// xi and 31-xi -> round-robin block->CU assignment gets constant per-CU work.
// qkv layout: [B, T, 3C]; head h: q at h*64, k at C + h*64, v at 2C + h*64.
// Logits = (q . k) * sqrt(C) = dot(32*q, k)   (faithful reference quirk).
// KV streamed in 32-row LDS tiles with online softmax.
// ---------------------------------------------------------------------------
__global__ __launch_bounds__(64) void attn_kernel(
    const float* __restrict__ qkv, float* __restrict__ ctx)
{
    __shared__ float Ks[32][64];
    __shared__ float Vs[32][64];

    const int lane = threadIdx.x;
    const int flat = blockIdx.x;          // 0..2047
    int xi         = flat & 31;           // q-tile index 0..31
    const int grp  = flat >> 5;           // 0..63
    if (grp & 1) xi = 31 - xi;            // anti-correlated work pairing
    const int h = grp & 15;
    const int b = grp >> 4;

    const int r0 = xi * 64;
    const int iq = r0 + lane;             // this thread's q row

    const float* qrow = qkv + (size_t)(b * T_SEQ + iq) * (3 * CEMB) + h * DHEAD;
    float q[DHEAD];
    #pragma unroll
    for (int c = 0; c < DHEAD; c += 4) {
        float4 f = *(const float4*)(qrow + c);
        q[c]     = f.x * 32.0f;
        q[c + 1] = f.y * 32.0f;
        q[c + 2] = f.z * 32.0f;
        q[c + 3] = f.w * 32.0f;
    }

    float o[DHEAD];
    #pragma unroll
    for (int c = 0; c < DHEAD; ++c) o[c] = 0.f;
    float m = -3.0e38f;
    float l = 0.f;

    const float* kbase = qkv + (size_t)(b * T_SEQ) * (3 * CEMB) + CEMB + h * DHEAD;
    const float* vbase = kbase + CEMB;

    const int ntile = (r0 >> 5) + 2;      // covers j <= r0 + 63

    for (int t = 0; t < ntile; ++t) {
        const int jt = t * 32;
        __syncthreads();
        // Wave loads K and V tiles: 512 float4 each -> 8 per lane per matrix.
        #pragma unroll
        for (int i = 0; i < 8; ++i) {
            int s  = lane + i * 64;       // 0..511
            int j  = s >> 4;              // 0..31
            int cq = (s & 15) * 4;        // 0..60
            *(float4*)&Ks[j][cq] = *(const float4*)(kbase + (size_t)(jt + j) * (3 * CEMB) + cq);
            *(float4*)&Vs[j][cq] = *(const float4*)(vbase + (size_t)(jt + j) * (3 * CEMB) + cq);
        }
        __syncthreads();

        float sv[32];
        float tmax = -3.0e38f;
        #pragma unroll
        for (int j = 0; j < 32; ++j) {
            float d0 = 0.f, d1 = 0.f, d2 = 0.f, d3 = 0.f;
            #pragma unroll
            for (int c = 0; c < DHEAD; c += 4) {
                float4 kk = *(const float4*)&Ks[j][c];
                d0 += q[c]     * kk.x;
                d1 += q[c + 1] * kk.y;
                d2 += q[c + 2] * kk.z;
                d3 += q[c + 3] * kk.w;
            }
            float d = (d0 + d1) + (d2 + d3);
            d = (jt + j <= iq) ? d : -3.0e38f;
            sv[j] = d;
            tmax = fmaxf(tmax, d);
        }
        float mnew  = fmaxf(m, tmax);
        float alpha = __expf(m - mnew);   // 0 on first tile, 1 when no new max
        l *= alpha;
        #pragma unroll
        for (int c = 0; c < DHEAD; ++c) o[c] *= alpha;
        m = mnew;

        #pragma unroll
        for (int j = 0; j < 32; ++j) {
            float p = __expf(sv[j] - m);  // masked -> underflows to exactly 0
            l += p;
            #pragma unroll
            for (int c = 0; c < DHEAD; c += 4) {
                float4 vv = *(const float4*)&Vs[j][c];
                o[c]     += p * vv.x;
                o[c + 1] += p * vv.y;
                o[c + 2] += p * vv.z;
                o[c + 3] += p * vv.w;
            }
        }
    }

    const float inv = 1.0f / l;
    float* orow = ctx + (size_t)(b * T_SEQ + iq) * CEMB + h * DHEAD;
    #pragma unroll
    for (int c = 0; c < DHEAD; c += 4) {
        float4 f;
        f.x = o[c] * inv;
        f.y = o[c + 1] * inv;
        f.z = o[c + 2] * inv;
        f.w = o[c + 3] * inv;
        *(float4*)(orow + c) = f;
    }
}

// ---------------------------------------------------------------------------
extern "C" void kernel_launch(void* const* d_in, const int* in_sizes, int n_in,
                              void* d_out, int out_size, void* d_ws, size_t ws_size,
                              hipStream_t stream)
{
    const float* x    = (const float*)d_in[0];   // [4,2048,1024]
    const float* Wqkv = (const float*)d_in[1];   // [1024,3072]
    const float* bqkv = (const float*)d_in[2];   // [3072]
    const float* Wo   = (const float*)d_in[3];   // [1024,1024]
    const float* bo   = (const float*)d_in[4];   // [1024]
    // d_in[5] = decoder (==1, causal hardcoded)
    float* out = (float*)d_out;                  // [4,2048,1024]

    float* qkv = (float*)d_ws;                       // 8192*3072 floats (96 MiB)
    float* ctx = qkv + (size_t)8192 * 3072;          // 8192*1024 floats (32 MiB)

    const int M = 4 * T_SEQ;  // 8192

    // 1) qkv = x @ Wqkv + bqkv
    gemm_bias_kernel<<<dim3(3 * CEMB / 128, M / 128), 256, 0, stream>>>(
        x, Wqkv, bqkv, qkv, M, 3 * CEMB, CEMB);

    // 2) causal attention -> ctx [B,T,C]  (2048 waves, work-balanced)
    attn_kernel<<<dim3(2048), 64, 0, stream>>>(qkv, ctx);

    // 3) out = ctx @ Wo + bo
    gemm_bias_kernel<<<dim3(CEMB / 128, M / 128), 256, 0, stream>>>(
        ctx, Wo, bo, out, M, CEMB, CEMB);
}

// Round 3
// 966.198 us; speedup vs baseline: 5.1968x; 5.1968x over previous
//
#include <hip/hip_runtime.h>
#include <cstdint>
#include <cstddef>

// Problem constants: B=4, T=2048, C=1024, H=16, d=64
#define T_SEQ 2048
#define CEMB  1024
#define NHEAD 16
#define DHEAD 64

typedef __attribute__((ext_vector_type(8))) short bf16x8;
typedef __attribute__((ext_vector_type(4))) float f32x4;

// float -> bf16 bits (RNE)
static __device__ __forceinline__ unsigned short f2bf(float x) {
    unsigned u = __builtin_bit_cast(unsigned, x);
    unsigned r = (u + 0x7FFFu + ((u >> 16) & 1u)) >> 16;
    return (unsigned short)r;
}
static __device__ __forceinline__ float bf2f(unsigned short b) {
    unsigned u = ((unsigned)b) << 16;
    return __builtin_bit_cast(float, u);
}

// ---------------------------------------------------------------------------
// GEMM with bias: C[M][N] = A[M][K](lda) @ B[K][N] + bias[N]   (fp32 vector)
// ---------------------------------------------------------------------------
__global__ __launch_bounds__(256) void gemm_bias_kernel(
    const float* __restrict__ A, const float* __restrict__ B,
    const float* __restrict__ bias, float* __restrict__ C,
    int M, int N, int K, int lda)
{
    __shared__ float As[16][128];   // [k][m]
    __shared__ float Bs[16][128];   // [k][n]

    const int tid = threadIdx.x;
    const int tx  = tid & 15;
    const int ty  = tid >> 4;

    const int row0 = blockIdx.y * 128;
    const int col0 = blockIdx.x * 128;

    float acc[2][2][4][4];
    #pragma unroll
    for (int a = 0; a < 2; ++a)
        #pragma unroll
        for (int b = 0; b < 2; ++b)
            #pragma unroll
            for (int i = 0; i < 4; ++i)
                #pragma unroll
                for (int j = 0; j < 4; ++j)
                    acc[a][b][i][j] = 0.f;

    const float* Ab = A + (size_t)row0 * lda;
    const float* Bb = B + col0;

    for (int kt = 0; kt < K; kt += 16) {
        __syncthreads();
        #pragma unroll
        for (int i = 0; i < 2; ++i) {
            int s  = tid + i * 256;
            int mm = s >> 2;
            int kq = s & 3;
            float4 f = *(const float4*)(Ab + (size_t)mm * lda + kt + kq * 4);
            As[kq * 4 + 0][mm] = f.x;
            As[kq * 4 + 1][mm] = f.y;
            As[kq * 4 + 2][mm] = f.z;
            As[kq * 4 + 3][mm] = f.w;
        }
        #pragma unroll
        for (int i = 0; i < 2; ++i) {
            int s  = tid + i * 256;
            int kk = s >> 5;
            int nq = s & 31;
            float4 f = *(const float4*)(Bb + (size_t)(kt + kk) * N + nq * 4);
            *(float4*)&Bs[kk][nq * 4] = f;
        }
        __syncthreads();

        #pragma unroll
        for (int k = 0; k < 16; ++k) {
            float4 a0 = *(const float4*)&As[k][ty * 4];
            float4 a1 = *(const float4*)&As[k][64 + ty * 4];
            float4 b0 = *(const float4*)&Bs[k][tx * 4];
            float4 b1 = *(const float4*)&Bs[k][64 + tx * 4];
            float av[2][4] = {{a0.x, a0.y, a0.z, a0.w}, {a1.x, a1.y, a1.z, a1.w}};
            float bv[2][4] = {{b0.x, b0.y, b0.z, b0.w}, {b1.x, b1.y, b1.z, b1.w}};
            #pragma unroll
            for (int ri = 0; ri < 2; ++ri)
                #pragma unroll
                for (int ci = 0; ci < 2; ++ci)
                    #pragma unroll
                    for (int i = 0; i < 4; ++i)
                        #pragma unroll
                        for (int j = 0; j < 4; ++j)
                            acc[ri][ci][i][j] += av[ri][i] * bv[ci][j];
        }
    }

    #pragma unroll
    for (int ri = 0; ri < 2; ++ri) {
        #pragma unroll
        for (int i = 0; i < 4; ++i) {
            int row = row0 + ri * 64 + ty * 4 + i;
            #pragma unroll
            for (int ci = 0; ci < 2; ++ci) {
                int col = col0 + ci * 64 + tx * 4;
                float4 bv = *(const float4*)(bias + col);
                float4 r;
                r.x = acc[ri][ci][i][0] + bv.x;
                r.y = acc[ri][ci][i][1] + bv.y;
                r.z = acc[ri][ci][i][2] + bv.z;
                r.w = acc[ri][ci][i][3] + bv.w;
                *(float4*)(C + (size_t)row * N + col) = r;
            }
        }
    }
}

// ---------------------------------------------------------------------------
// Repack V: qkv fp32 [B,T,3C] (V at col 2C + h*64) -> Vt bf16 [B][H][64][T]
// ---------------------------------------------------------------------------
__global__ __launch_bounds__(256) void repack_vt_kernel(
    const float* __restrict__ qkv, short* __restrict__ vt)
{
    __shared__ short tile[64][80];   // [t_local][d], padded (160B rows, 16B-aligned)

    const int tid = threadIdx.x;
    const int tt  = blockIdx.x;      // t-tile 0..31
    const int h   = blockIdx.y;
    const int b   = blockIdx.z;
    const int t0  = tt * 64;

    {
        int tr   = tid >> 2;             // 0..63 local t
        int cgrp = tid & 3;              // 16-col group
        const float* src = qkv + (size_t)(b * T_SEQ + t0 + tr) * (3 * CEMB)
                               + 2 * CEMB + h * DHEAD + cgrp * 16;
        short tmp[16];
        #pragma unroll
        for (int q = 0; q < 4; ++q) {
            float4 f = *(const float4*)(src + q * 4);
            tmp[q * 4 + 0] = (short)f2bf(f.x);
            tmp[q * 4 + 1] = (short)f2bf(f.y);
            tmp[q * 4 + 2] = (short)f2bf(f.z);
            tmp[q * 4 + 3] = (short)f2bf(f.w);
        }
        #pragma unroll
        for (int q = 0; q < 2; ++q) {
            bf16x8 v;
            #pragma unroll
            for (int e = 0; e < 8; ++e) v[e] = tmp[q * 8 + e];
            *(bf16x8*)&tile[tr][cgrp * 16 + q * 8] = v;
        }
    }
    __syncthreads();
    {
        int d  = tid >> 2;               // 0..63
        int tc = tid & 3;                // 16-t group
        short s[16];
        #pragma unroll
        for (int e = 0; e < 16; ++e) s[e] = tile[tc * 16 + e][d];
        short* dst = vt + ((size_t)((b * NHEAD + h) * DHEAD + d)) * T_SEQ + t0 + tc * 16;
        bf16x8 v0, v1;
        #pragma unroll
        for (int e = 0; e < 8; ++e) { v0[e] = s[e]; v1[e] = s[8 + e]; }
        *(bf16x8*)dst       = v0;
        *(bf16x8*)(dst + 8) = v1;
    }
}

// ---------------------------------------------------------------------------
// MFMA flash attention (causal).
//  - 512 blocks x 256 threads (4 waves). Block bid: pr=bid&7, bh=bid>>3.
//    Runs q-tile xi=pr then xi=15-pr  -> constant 36 KV-steps per block.
//  - Wave w owns 32 q-rows. Q: fp32 from qkv, x32 scale, hi/lo bf16 split in regs.
//  - QK^T: 3-MFMA bf16x2 split (fp32-level logits; softmax is near-one-hot).
//  - K staged fp32->hi/lo bf16 in LDS, XOR-swizzled ((row&7) chunk swizzle).
//  - V from pre-transposed Vt bf16, staged in swizzled LDS.
//  - P bounced через per-wave swizzled LDS as bf16; PV in plain bf16 MFMA.
// MFMA mappings (guide-verified): A: row=l&15, k=(l>>4)*8+e; B: col=l&15,
// k=(l>>4)*8+e; C/D: col=l&15, row=(l>>4)*4+reg.
// ---------------------------------------------------------------------------
__global__ __launch_bounds__(256) void attn_mfma_kernel(
    const float* __restrict__ qkv, const short* __restrict__ vt,
    float* __restrict__ ctx)   // ctx has row stride 3*CEMB (aliases qkv V region)
{
    __shared__ __align__(16) short K_hi[64 * 64];
    __shared__ __align__(16) short K_lo[64 * 64];
    __shared__ __align__(16) short Vs[64 * 64];
    __shared__ __align__(16) short Ps[4 * 32 * 64];

    const int tid = threadIdx.x;
    const int w   = tid >> 6;        // wave 0..3
    const int l   = tid & 63;
    const int lr  = l & 15;
    const int lg  = l >> 4;

    const int bid = blockIdx.x;
    const int pr  = bid & 7;
    const int bh  = bid >> 3;
    const int h   = bh & 15;
    const int b   = bh >> 4;

    const float* kglob = qkv + (size_t)(b * T_SEQ) * (3 * CEMB) + CEMB + h * DHEAD;
    const short* vglob = vt + ((size_t)((b * NHEAD + h) * DHEAD)) * T_SEQ;

    for (int half = 0; half < 2; ++half) {
        const int xi = half ? (15 - pr) : pr;
        const int q0 = xi * 128;
        const int qw = q0 + w * 32;

        // ---- Load Q fragments (fp32 -> x32 -> hi/lo bf16 split) ----
        bf16x8 ahi[2][2], alo[2][2];
        #pragma unroll
        for (int rt = 0; rt < 2; ++rt) {
            #pragma unroll
            for (int kk = 0; kk < 2; ++kk) {
                int row = qw + rt * 16 + lr;
                const float* qsrc = qkv + (size_t)(b * T_SEQ + row) * (3 * CEMB)
                                        + h * DHEAD + kk * 32 + lg * 8;
                float4 fa = *(const float4*)qsrc;
                float4 fb = *(const float4*)(qsrc + 4);
                float v[8] = {fa.x, fa.y, fa.z, fa.w, fb.x, fb.y, fb.z, fb.w};
                #pragma unroll
                for (int e = 0; e < 8; ++e) {
                    float x = v[e] * 32.0f;
                    unsigned short hb = f2bf(x);
                    float hf = bf2f(hb);
                    unsigned short lb = f2bf(x - hf);
                    ahi[rt][kk][e] = (short)hb;
                    alo[rt][kk][e] = (short)lb;
                }
            }
        }

        f32x4 O[2][4];
        #pragma unroll
        for (int rt = 0; rt < 2; ++rt)
            #pragma unroll
            for (int dt = 0; dt < 4; ++dt)
                O[rt][dt] = (f32x4){0.f, 0.f, 0.f, 0.f};
        float mrun[2][4], lrun[2][4];
        #pragma unroll
        for (int rt = 0; rt < 2; ++rt)
            #pragma unroll
            for (int r = 0; r < 4; ++r) { mrun[rt][r] = -3.0e38f; lrun[rt][r] = 0.f; }

        const int nsteps = 2 * xi + 2;
        for (int t = 0; t < nsteps; ++t) {
            const int j0 = t * 64;
            __syncthreads();   // prior-step readers done before overwrite

            // ---- Stage K tile: fp32 -> hi/lo bf16, XOR-swizzled ----
            {
                int jr = tid >> 2;          // key row 0..63
                int cp = tid & 3;           // 16-col group
                const float* ks = kglob + (size_t)(j0 + jr) * (3 * CEMB) + cp * 16;
                float kv[16];
                #pragma unroll
                for (int q = 0; q < 4; ++q) {
                    float4 f = *(const float4*)(ks + q * 4);
                    kv[q * 4 + 0] = f.x; kv[q * 4 + 1] = f.y;
                    kv[q * 4 + 2] = f.z; kv[q * 4 + 3] = f.w;
                }
                #pragma unroll
                for (int c2 = 0; c2 < 2; ++c2) {
                    int chunk = cp * 2 + c2;
                    bf16x8 hv, lv;
                    #pragma unroll
                    for (int e = 0; e < 8; ++e) {
                        float x = kv[c2 * 8 + e];
                        unsigned short hb = f2bf(x);
                        float hf = bf2f(hb);
                        hv[e] = (short)hb;
                        lv[e] = (short)f2bf(x - hf);
                    }
                    int idx = jr * 64 + ((chunk ^ (jr & 7)) << 3);
                    *(bf16x8*)&K_hi[idx] = hv;
                    *(bf16x8*)&K_lo[idx] = lv;
                }
            }
            // ---- Stage V tile from Vt (bf16), XOR-swizzled ----
            {
                int dr = tid >> 2;          // d row 0..63
                int vc = tid & 3;
                const short* vsrc = vglob + (size_t)dr * T_SEQ + j0 + vc * 16;
                bf16x8 v0 = *(const bf16x8*)vsrc;
                bf16x8 v1 = *(const bf16x8*)(vsrc + 8);
                int i0 = dr * 64 + (((vc * 2) ^ (dr & 7)) << 3);
                int i1 = dr * 64 + (((vc * 2 + 1) ^ (dr & 7)) << 3);
                *(bf16x8*)&Vs[i0] = v0;
                *(bf16x8*)&Vs[i1] = v1;
            }
            __syncthreads();

            // ---- Per-wave compute ----
            #pragma unroll
            for (int rt = 0; rt < 2; ++rt) {
                // QK^T: S[ct] 16x16 tiles, 3-MFMA split
                f32x4 S[4];
                #pragma unroll
                for (int ct = 0; ct < 4; ++ct) {
                    f32x4 s = (f32x4){0.f, 0.f, 0.f, 0.f};
                    #pragma unroll
                    for (int kk = 0; kk < 2; ++kk) {
                        int j  = ct * 16 + lr;
                        int ck = kk * 4 + lg;
                        int idx = j * 64 + ((ck ^ (j & 7)) << 3);
                        bf16x8 bh8 = *(bf16x8*)&K_hi[idx];
                        bf16x8 bl8 = *(bf16x8*)&K_lo[idx];
                        s = __builtin_amdgcn_mfma_f32_16x16x32_bf16(ahi[rt][kk], bh8, s, 0, 0, 0);
                        s = __builtin_amdgcn_mfma_f32_16x16x32_bf16(alo[rt][kk], bh8, s, 0, 0, 0);
                        s = __builtin_amdgcn_mfma_f32_16x16x32_bf16(ahi[rt][kk], bl8, s, 0, 0, 0);
                    }
                    // causal mask
                    if (j0 + ct * 16 + 15 > qw + rt * 16) {
                        int jabs = j0 + ct * 16 + lr;
                        #pragma unroll
                        for (int r = 0; r < 4; ++r) {
                            int qabs = qw + rt * 16 + lg * 4 + r;
                            s[r] = (jabs <= qabs) ? s[r] : -3.0e38f;
                        }
                    }
                    S[ct] = s;
                }

                // online softmax (per row r; replicated across the 16-lane group)
                float tm[4], mnew[4], alpha[4], lsum[4];
                #pragma unroll
                for (int r = 0; r < 4; ++r) {
                    float v = fmaxf(fmaxf(S[0][r], S[1][r]), fmaxf(S[2][r], S[3][r]));
                    v = fmaxf(v, __shfl_xor(v, 1));
                    v = fmaxf(v, __shfl_xor(v, 2));
                    v = fmaxf(v, __shfl_xor(v, 4));
                    v = fmaxf(v, __shfl_xor(v, 8));
                    tm[r] = v;
                    mnew[r]  = fmaxf(mrun[rt][r], v);
                    alpha[r] = __expf(mrun[rt][r] - mnew[r]);
                    mrun[rt][r] = mnew[r];
                    lsum[r] = 0.f;
                }
                // P = exp(S - m), write to per-wave swizzled LDS as bf16
                #pragma unroll
                for (int ct = 0; ct < 4; ++ct) {
                    #pragma unroll
                    for (int r = 0; r < 4; ++r) {
                        float p = __expf(S[ct][r] - mnew[r]);
                        lsum[r] += p;
                        int row = rt * 16 + lg * 4 + r;
                        int col = ct * 16 + lr;
                        Ps[w * 2048 + row * 64 + (col ^ ((row & 7) << 3))] = (short)f2bf(p);
                    }
                }
                #pragma unroll
                for (int r = 0; r < 4; ++r) {
                    float s = lsum[r];
                    s += __shfl_xor(s, 1);
                    s += __shfl_xor(s, 2);
                    s += __shfl_xor(s, 4);
                    s += __shfl_xor(s, 8);
                    lrun[rt][r] = lrun[rt][r] * alpha[r] + s;
                }
                // rescale O
                #pragma unroll
                for (int dt = 0; dt < 4; ++dt)
                    #pragma unroll
                    for (int r = 0; r < 4; ++r)
                        O[rt][dt][r] *= alpha[r];
            }

            __builtin_amdgcn_wave_barrier();  // order P writes before P reads

            // PV: O += P @ V   (per wave, own Ps region)
            #pragma unroll
            for (int rt = 0; rt < 2; ++rt) {
                bf16x8 pa[2];
                #pragma unroll
                for (int jk = 0; jk < 2; ++jk) {
                    int row = rt * 16 + lr;
                    int ck  = jk * 4 + lg;
                    int idx = w * 2048 + row * 64 + ((ck ^ (row & 7)) << 3);
                    pa[jk] = *(bf16x8*)&Ps[idx];
                }
                #pragma unroll
                for (int dt = 0; dt < 4; ++dt) {
                    #pragma unroll
                    for (int jk = 0; jk < 2; ++jk) {
                        int d   = dt * 16 + lr;
                        int ck  = jk * 4 + lg;
                        int idx = d * 64 + ((ck ^ (d & 7)) << 3);
                        bf16x8 vb = *(bf16x8*)&Vs[idx];
                        O[rt][dt] = __builtin_amdgcn_mfma_f32_16x16x32_bf16(pa[jk], vb, O[rt][dt], 0, 0, 0);
                    }
                }
            }
        }

        // ---- Epilogue: O / l -> ctx (row stride 3C) ----
        #pragma unroll
        for (int rt = 0; rt < 2; ++rt) {
            #pragma unroll
            for (int r = 0; r < 4; ++r) {
                float inv = 1.0f / lrun[rt][r];
                int row = qw + rt * 16 + lg * 4 + r;
                #pragma unroll
                for (int dt = 0; dt < 4; ++dt) {
                    int col = h * DHEAD + dt * 16 + lr;
                    ctx[(size_t)(b * T_SEQ + row) * (3 * CEMB) + col] = O[rt][dt][r] * inv;
                }
            }
        }
    }
}

// ---------------------------------------------------------------------------
extern "C" void kernel_launch(void* const* d_in, const int* in_sizes, int n_in,
                              void* d_out, int out_size, void* d_ws, size_t ws_size,
                              hipStream_t stream)
{
    const float* x    = (const float*)d_in[0];
    const float* Wqkv = (const float*)d_in[1];
    const float* bqkv = (const float*)d_in[2];
    const float* Wo   = (const float*)d_in[3];
    const float* bo   = (const float*)d_in[4];
    float* out = (float*)d_out;

    float* qkv = (float*)d_ws;                               // 8192*3072 fp32 (96 MiB)
    short* vt  = (short*)(qkv + (size_t)8192 * 3072);        // 8192*1024 bf16 (16 MiB)
    float* ctx = qkv + 2 * CEMB;  // aliases qkv V region (cols 2C..3C), stride 3C

    const int M = 4 * T_SEQ;  // 8192

    // 1) qkv = x @ Wqkv + bqkv
    gemm_bias_kernel<<<dim3(3 * CEMB / 128, M / 128), 256, 0, stream>>>(
        x, Wqkv, bqkv, qkv, M, 3 * CEMB, CEMB, CEMB);

    // 2) repack V -> Vt bf16 [B][H][64][T]
    repack_vt_kernel<<<dim3(T_SEQ / 64, NHEAD, 4), 256, 0, stream>>>(qkv, vt);

    // 3) causal MFMA flash attention -> ctx (V region of qkv, stride 3C)
    attn_mfma_kernel<<<dim3(512), 256, 0, stream>>>(qkv, vt, ctx);

    // 4) out = ctx @ Wo + bo
    gemm_bias_kernel<<<dim3(CEMB / 128, M / 128), 256, 0, stream>>>(
        ctx, Wo, bo, out, M, CEMB, CEMB, 3 * CEMB);
}

// Round 4
// 391.382 us; speedup vs baseline: 12.8291x; 2.4687x over previous
//
#include <hip/hip_runtime.h>
#include <cstdint>
#include <cstddef>

// Problem constants: B=4, T=2048, C=1024, H=16, d=64
#define T_SEQ 2048
#define CEMB  1024
#define NHEAD 16
#define DHEAD 64

typedef __attribute__((ext_vector_type(8))) short bf16x8;
typedef __attribute__((ext_vector_type(4))) float f32x4;

static __device__ __forceinline__ unsigned short f2bf(float x) {
    unsigned u = __builtin_bit_cast(unsigned, x);
    unsigned r = (u + 0x7FFFu + ((u >> 16) & 1u)) >> 16;
    return (unsigned short)r;
}
static __device__ __forceinline__ float bf2f(unsigned short b) {
    unsigned u = ((unsigned)b) << 16;
    return __builtin_bit_cast(float, u);
}

// async global->LDS: 16B per lane; ldsbase wave-uniform, lane offset = lane*16B.
static __device__ __forceinline__ void gload16(const short* gsrc, short* ldsbase) {
    __builtin_amdgcn_global_load_lds(
        (const __attribute__((address_space(1))) void*)gsrc,
        (__attribute__((address_space(3))) void*)ldsbase, 16, 0, 0);
}

// ---------------------------------------------------------------------------
// MFMA GEMM, 128x128 tile, BK=32, 256 threads (4 waves, 2x2).
//   C[M][N] = A[M][K] @ B^T[N][K]^T + bias[N]
// SPLIT==3: A,B split hi/lo bf16, 3 MFMAs (hh+lh+hl) -> ~fp32 product.
// A_F32: A read fp32, split in staging (VALU). Else A bf16 via global_load_lds.
// LDS layout per component: [4 kc][128 row][8 elems] (16B granules).
// MFMA 16x16x32 mappings (validated R3): A row=l&15,k=(l>>4)*8+e; B col=l&15,
// same k; D col=l&15, row=(l>>4)*4+reg.
// ---------------------------------------------------------------------------
template<int SPLIT, bool A_F32, bool OUT_BF16>
__global__ __launch_bounds__(256) void gemm_mfma_kernel(
    const float* __restrict__ Af,   // A fp32 [M][K]   (A_F32)
    const short* __restrict__ Ah,   // A bf16 [M][K]   (!A_F32)
    const short* __restrict__ Bh,   // B^T hi [N][K]
    const short* __restrict__ Bl,   // B^T lo [N][K]   (SPLIT==3)
    const float* __restrict__ bias,
    void* __restrict__ Cout, int K, int ldc)
{
    // shorts: A_hi @0, B_hi @4096, A_lo @8192, B_lo @12288
    __shared__ __align__(16) short smem[(SPLIT == 3) ? 16384 : 8192];

    const int tid = threadIdx.x;
    const int w = tid >> 6, l = tid & 63;
    const int lr = l & 15, lg = l >> 4;
    const int wr = w >> 1, wc = w & 1;
    const int row0 = blockIdx.y * 128;
    const int col0 = blockIdx.x * 128;

    f32x4 acc[4][4];
    #pragma unroll
    for (int mt = 0; mt < 4; ++mt)
        #pragma unroll
        for (int nt = 0; nt < 4; ++nt)
            acc[mt][nt] = (f32x4){0.f, 0.f, 0.f, 0.f};

    // staging slots (gload path): wave w, issues i=0,1 -> slots w*128+i*64+l
    const int sB0 = w * 128 + l, sB1 = sB0 + 64;
    const short* gB0 = Bh + (size_t)(col0 + (sB0 & 127)) * K + (sB0 >> 7) * 8;
    const short* gB1 = Bh + (size_t)(col0 + (sB1 & 127)) * K + (sB1 >> 7) * 8;
    short* dB0 = &smem[4096 + (w * 128) * 8];
    short* dB1 = &smem[4096 + (w * 128 + 64) * 8];
    const short* gBl0 = nullptr; const short* gBl1 = nullptr;
    if constexpr (SPLIT == 3) {
        gBl0 = Bl + (size_t)(col0 + (sB0 & 127)) * K + (sB0 >> 7) * 8;
        gBl1 = Bl + (size_t)(col0 + (sB1 & 127)) * K + (sB1 >> 7) * 8;
    }

    // A gload path
    const short* gA0 = nullptr; const short* gA1 = nullptr;
    if constexpr (!A_F32) {
        gA0 = Ah + (size_t)(row0 + (sB0 & 127)) * K + (sB0 >> 7) * 8;
        gA1 = Ah + (size_t)(row0 + (sB1 & 127)) * K + (sB1 >> 7) * 8;
    }
    short* dA0 = &smem[(w * 128) * 8];
    short* dA1 = &smem[(w * 128 + 64) * 8];

    // A fp32 reg-stage path: thread covers row=tid>>1, 16 consecutive k
    const int arow = tid >> 1, ahalf = tid & 1;
    const float* gAf = A_F32 ? (Af + (size_t)(row0 + arow) * K + ahalf * 16) : nullptr;

    for (int kt = 0; kt < K; kt += 32) {
        __syncthreads();
        if constexpr (!A_F32) {
            gload16(gA0 + kt, dA0);
            gload16(gA1 + kt, dA1);
        }
        gload16(gB0 + kt, dB0);
        gload16(gB1 + kt, dB1);
        if constexpr (SPLIT == 3) {
            gload16(gBl0 + kt, &smem[12288 + (w * 128) * 8]);
            gload16(gBl1 + kt, &smem[12288 + (w * 128 + 64) * 8]);
        }
        if constexpr (A_F32) {
            const float* src = gAf + kt;
            float4 f0 = *(const float4*)(src);
            float4 f1 = *(const float4*)(src + 4);
            float4 f2 = *(const float4*)(src + 8);
            float4 f3 = *(const float4*)(src + 12);
            float xs[16] = {f0.x, f0.y, f0.z, f0.w, f1.x, f1.y, f1.z, f1.w,
                            f2.x, f2.y, f2.z, f2.w, f3.x, f3.y, f3.z, f3.w};
            #pragma unroll
            for (int q = 0; q < 2; ++q) {
                bf16x8 h8, l8;
                #pragma unroll
                for (int e = 0; e < 8; ++e) {
                    float x = xs[q * 8 + e];
                    if constexpr (SPLIT == 3) {
                        unsigned u = __builtin_bit_cast(unsigned, x);
                        h8[e] = (short)(unsigned short)(u >> 16);          // trunc hi
                        float hf = __builtin_bit_cast(float, u & 0xFFFF0000u);
                        l8[e] = (short)f2bf(x - hf);                       // exact tail
                    } else {
                        h8[e] = (short)f2bf(x);
                    }
                }
                int slot = (ahalf * 2 + q) * 128 + arow;
                *(bf16x8*)&smem[slot * 8] = h8;
                if constexpr (SPLIT == 3) *(bf16x8*)&smem[8192 + slot * 8] = l8;
            }
        }
        __syncthreads();

        const int aoff = (lg * 128 + wr * 64 + lr) * 8;
        const int boff = 4096 + (lg * 128 + wc * 64 + lr) * 8;
        bf16x8 ahf[4], alf[4];
        #pragma unroll
        for (int mt = 0; mt < 4; ++mt) {
            ahf[mt] = *(const bf16x8*)&smem[aoff + mt * 128];
            if constexpr (SPLIT == 3)
                alf[mt] = *(const bf16x8*)&smem[8192 + aoff + mt * 128];
        }
        #pragma unroll
        for (int nt = 0; nt < 4; ++nt) {
            bf16x8 bhf = *(const bf16x8*)&smem[boff + nt * 128];
            if constexpr (SPLIT == 3) {
                bf16x8 blf = *(const bf16x8*)&smem[8192 + boff + nt * 128];
                #pragma unroll
                for (int mt = 0; mt < 4; ++mt) {
                    acc[mt][nt] = __builtin_amdgcn_mfma_f32_16x16x32_bf16(ahf[mt], bhf, acc[mt][nt], 0, 0, 0);
                    acc[mt][nt] = __builtin_amdgcn_mfma_f32_16x16x32_bf16(alf[mt], bhf, acc[mt][nt], 0, 0, 0);
                    acc[mt][nt] = __builtin_amdgcn_mfma_f32_16x16x32_bf16(ahf[mt], blf, acc[mt][nt], 0, 0, 0);
                }
            } else {
                #pragma unroll
                for (int mt = 0; mt < 4; ++mt)
                    acc[mt][nt] = __builtin_amdgcn_mfma_f32_16x16x32_bf16(ahf[mt], bhf, acc[mt][nt], 0, 0, 0);
            }
        }
    }

    #pragma unroll
    for (int mt = 0; mt < 4; ++mt) {
        #pragma unroll
        for (int r = 0; r < 4; ++r) {
            int m = row0 + wr * 64 + mt * 16 + lg * 4 + r;
            #pragma unroll
            for (int nt = 0; nt < 4; ++nt) {
                int n = col0 + wc * 64 + nt * 16 + lr;
                float v = acc[mt][nt][r] + bias[n];
                if constexpr (OUT_BF16)
                    ((short*)Cout)[(size_t)m * ldc + n] = (short)f2bf(v);
                else
                    ((float*)Cout)[(size_t)m * ldc + n] = v;
            }
        }
    }
}

// ---------------------------------------------------------------------------
// Transpose + hi/lo bf16 split: src fp32 [Krows][nsrc] -> hi/lo [N][1024]
// 64x64 tiles. lo may be nullptr (hi only).
// ---------------------------------------------------------------------------
__global__ __launch_bounds__(256) void transpose_split_kernel(
    const float* __restrict__ src, int nsrc,
    short* __restrict__ hi, short* __restrict__ lo)
{
    __shared__ float tile[64][68];
    const int tid = threadIdx.x;
    const int n0 = blockIdx.x * 64, k0 = blockIdx.y * 64;
    {
        int kr = tid >> 2, cg = tid & 3;
        const float* s = src + (size_t)(k0 + kr) * nsrc + n0 + cg * 16;
        #pragma unroll
        for (int q = 0; q < 4; ++q) {
            float4 f = *(const float4*)(s + q * 4);
            tile[kr][cg * 16 + q * 4 + 0] = f.x;
            tile[kr][cg * 16 + q * 4 + 1] = f.y;
            tile[kr][cg * 16 + q * 4 + 2] = f.z;
            tile[kr][cg * 16 + q * 4 + 3] = f.w;
        }
    }
    __syncthreads();
    {
        int nr = tid >> 2, kg = tid & 3;
        int n = n0 + nr;
        bf16x8 h0, h1, lo0, lo1;
        #pragma unroll
        for (int e = 0; e < 8; ++e) {
            float a = tile[kg * 16 + e][nr];
            float b = tile[kg * 16 + 8 + e][nr];
            unsigned short ha = f2bf(a), hb = f2bf(b);
            h0[e] = (short)ha; h1[e] = (short)hb;
            lo0[e] = (short)f2bf(a - bf2f(ha));
            lo1[e] = (short)f2bf(b - bf2f(hb));
        }
        short* dh = hi + (size_t)n * 1024 + k0 + kg * 16;
        *(bf16x8*)dh = h0;
        *(bf16x8*)(dh + 8) = h1;
        if (lo) {
            short* dl = lo + (size_t)n * 1024 + k0 + kg * 16;
            *(bf16x8*)dl = lo0;
            *(bf16x8*)(dl + 8) = lo1;
        }
    }
}

// ---------------------------------------------------------------------------
// Repack V: v bf16 [B*T][C] (head h cols h*64..) -> Vt bf16 [B][H][64][T]
// ---------------------------------------------------------------------------
__global__ __launch_bounds__(256) void repack_vt_kernel(
    const short* __restrict__ v, short* __restrict__ vt)
{
    __shared__ short tile[64][80];
    const int tid = threadIdx.x;
    const int tt = blockIdx.x, h = blockIdx.y, b = blockIdx.z;
    const int t0 = tt * 64;
    {
        int tr = tid >> 2, cgrp = tid & 3;
        const short* src = v + (size_t)(b * T_SEQ + t0 + tr) * CEMB + h * DHEAD + cgrp * 16;
        *(bf16x8*)&tile[tr][cgrp * 16]     = *(const bf16x8*)src;
        *(bf16x8*)&tile[tr][cgrp * 16 + 8] = *(const bf16x8*)(src + 8);
    }
    __syncthreads();
    {
        int d = tid >> 2, tc = tid & 3;
        short s[16];
        #pragma unroll
        for (int e = 0; e < 16; ++e) s[e] = tile[tc * 16 + e][d];
        short* dst = vt + ((size_t)((b * NHEAD + h) * DHEAD + d)) * T_SEQ + t0 + tc * 16;
        bf16x8 v0, v1;
        #pragma unroll
        for (int e = 0; e < 8; ++e) { v0[e] = s[e]; v1[e] = s[8 + e]; }
        *(bf16x8*)dst       = v0;
        *(bf16x8*)(dst + 8) = v1;
    }
}

// ---------------------------------------------------------------------------
// MFMA flash attention (causal), as validated in R3, with new I/O:
//  - qk fp32 [B*T][2048] (q cols 0..1023, k cols 1024..2047)
//  - Vt bf16 [B][H][64][T]
//  - ctx written bf16 [B*T][1024]
// ---------------------------------------------------------------------------
__global__ __launch_bounds__(256) void attn_mfma_kernel(
    const float* __restrict__ qk, const short* __restrict__ vt,
    short* __restrict__ ctxb)
{
    __shared__ __align__(16) short K_hi[64 * 64];
    __shared__ __align__(16) short K_lo[64 * 64];
    __shared__ __align__(16) short Vs[64 * 64];
    __shared__ __align__(16) short Ps[4 * 32 * 64];

    const int tid = threadIdx.x;
    const int w   = tid >> 6;
    const int l   = tid & 63;
    const int lr  = l & 15;
    const int lg  = l >> 4;

    const int bid = blockIdx.x;
    const int pr  = bid & 7;
    const int bh  = bid >> 3;
    const int h   = bh & 15;
    const int b   = bh >> 4;

    const float* kglob = qk + (size_t)(b * T_SEQ) * 2048 + CEMB + h * DHEAD;
    const short* vglob = vt + ((size_t)((b * NHEAD + h) * DHEAD)) * T_SEQ;

    for (int half = 0; half < 2; ++half) {
        const int xi = half ? (15 - pr) : pr;
        const int q0 = xi * 128;
        const int qw = q0 + w * 32;

        bf16x8 ahi[2][2], alo[2][2];
        #pragma unroll
        for (int rt = 0; rt < 2; ++rt) {
            #pragma unroll
            for (int kk = 0; kk < 2; ++kk) {
                int row = qw + rt * 16 + lr;
                const float* qsrc = qk + (size_t)(b * T_SEQ + row) * 2048
                                      + h * DHEAD + kk * 32 + lg * 8;
                float4 fa = *(const float4*)qsrc;
                float4 fb = *(const float4*)(qsrc + 4);
                float v[8] = {fa.x, fa.y, fa.z, fa.w, fb.x, fb.y, fb.z, fb.w};
                #pragma unroll
                for (int e = 0; e < 8; ++e) {
                    float x = v[e] * 32.0f;
                    unsigned short hb = f2bf(x);
                    float hf = bf2f(hb);
                    unsigned short lb = f2bf(x - hf);
                    ahi[rt][kk][e] = (short)hb;
                    alo[rt][kk][e] = (short)lb;
                }
            }
        }

        f32x4 O[2][4];
        #pragma unroll
        for (int rt = 0; rt < 2; ++rt)
            #pragma unroll
            for (int dt = 0; dt < 4; ++dt)
                O[rt][dt] = (f32x4){0.f, 0.f, 0.f, 0.f};
        float mrun[2][4], lrun[2][4];
        #pragma unroll
        for (int rt = 0; rt < 2; ++rt)
            #pragma unroll
            for (int r = 0; r < 4; ++r) { mrun[rt][r] = -3.0e38f; lrun[rt][r] = 0.f; }

        const int nsteps = 2 * xi + 2;
        for (int t = 0; t < nsteps; ++t) {
            const int j0 = t * 64;
            __syncthreads();

            {   // stage K: fp32 -> hi/lo bf16, XOR-swizzled
                int jr = tid >> 2;
                int cp = tid & 3;
                const float* ks = kglob + (size_t)(j0 + jr) * 2048 + cp * 16;
                float kv[16];
                #pragma unroll
                for (int q = 0; q < 4; ++q) {
                    float4 f = *(const float4*)(ks + q * 4);
                    kv[q * 4 + 0] = f.x; kv[q * 4 + 1] = f.y;
                    kv[q * 4 + 2] = f.z; kv[q * 4 + 3] = f.w;
                }
                #pragma unroll
                for (int c2 = 0; c2 < 2; ++c2) {
                    int chunk = cp * 2 + c2;
                    bf16x8 hv, lv;
                    #pragma unroll
                    for (int e = 0; e < 8; ++e) {
                        float x = kv[c2 * 8 + e];
                        unsigned short hb = f2bf(x);
                        float hf = bf2f(hb);
                        hv[e] = (short)hb;
                        lv[e] = (short)f2bf(x - hf);
                    }
                    int idx = jr * 64 + ((chunk ^ (jr & 7)) << 3);
                    *(bf16x8*)&K_hi[idx] = hv;
                    *(bf16x8*)&K_lo[idx] = lv;
                }
            }
            {   // stage V from Vt (bf16), XOR-swizzled
                int dr = tid >> 2;
                int vc = tid & 3;
                const short* vsrc = vglob + (size_t)dr * T_SEQ + j0 + vc * 16;
                bf16x8 v0 = *(const bf16x8*)vsrc;
                bf16x8 v1 = *(const bf16x8*)(vsrc + 8);
                int i0 = dr * 64 + (((vc * 2) ^ (dr & 7)) << 3);
                int i1 = dr * 64 + (((vc * 2 + 1) ^ (dr & 7)) << 3);
                *(bf16x8*)&Vs[i0] = v0;
                *(bf16x8*)&Vs[i1] = v1;
            }
            __syncthreads();

            #pragma unroll
            for (int rt = 0; rt < 2; ++rt) {
                f32x4 S[4];
                #pragma unroll
                for (int ct = 0; ct < 4; ++ct) {
                    f32x4 s = (f32x4){0.f, 0.f, 0.f, 0.f};
                    #pragma unroll
                    for (int kk = 0; kk < 2; ++kk) {
                        int j  = ct * 16 + lr;
                        int ck = kk * 4 + lg;
                        int idx = j * 64 + ((ck ^ (j & 7)) << 3);
                        bf16x8 bh8 = *(bf16x8*)&K_hi[idx];
                        bf16x8 bl8 = *(bf16x8*)&K_lo[idx];
                        s = __builtin_amdgcn_mfma_f32_16x16x32_bf16(ahi[rt][kk], bh8, s, 0, 0, 0);
                        s = __builtin_amdgcn_mfma_f32_16x16x32_bf16(alo[rt][kk], bh8, s, 0, 0, 0);
                        s = __builtin_amdgcn_mfma_f32_16x16x32_bf16(ahi[rt][kk], bl8, s, 0, 0, 0);
                    }
                    if (j0 + ct * 16 + 15 > qw + rt * 16) {
                        int jabs = j0 + ct * 16 + lr;
                        #pragma unroll
                        for (int r = 0; r < 4; ++r) {
                            int qabs = qw + rt * 16 + lg * 4 + r;
                            s[r] = (jabs <= qabs) ? s[r] : -3.0e38f;
                        }
                    }
                    S[ct] = s;
                }

                float mnew[4], alpha[4], lsum[4];
                #pragma unroll
                for (int r = 0; r < 4; ++r) {
                    float v = fmaxf(fmaxf(S[0][r], S[1][r]), fmaxf(S[2][r], S[3][r]));
                    v = fmaxf(v, __shfl_xor(v, 1));
                    v = fmaxf(v, __shfl_xor(v, 2));
                    v = fmaxf(v, __shfl_xor(v, 4));
                    v = fmaxf(v, __shfl_xor(v, 8));
                    mnew[r]  = fmaxf(mrun[rt][r], v);
                    alpha[r] = __expf(mrun[rt][r] - mnew[r]);
                    mrun[rt][r] = mnew[r];
                    lsum[r] = 0.f;
                }
                #pragma unroll
                for (int ct = 0; ct < 4; ++ct) {
                    #pragma unroll
                    for (int r = 0; r < 4; ++r) {
                        float p = __expf(S[ct][r] - mnew[r]);
                        lsum[r] += p;
                        int row = rt * 16 + lg * 4 + r;
                        int col = ct * 16 + lr;
                        Ps[w * 2048 + row * 64 + (col ^ ((row & 7) << 3))] = (short)f2bf(p);
                    }
                }
                #pragma unroll
                for (int r = 0; r < 4; ++r) {
                    float s = lsum[r];
                    s += __shfl_xor(s, 1);
                    s += __shfl_xor(s, 2);
                    s += __shfl_xor(s, 4);
                    s += __shfl_xor(s, 8);
                    lrun[rt][r] = lrun[rt][r] * alpha[r] + s;
                }
                #pragma unroll
                for (int dt = 0; dt < 4; ++dt)
                    #pragma unroll
                    for (int r = 0; r < 4; ++r)
                        O[rt][dt][r] *= alpha[r];
            }

            __builtin_amdgcn_wave_barrier();

            #pragma unroll
            for (int rt = 0; rt < 2; ++rt) {
                bf16x8 pa[2];
                #pragma unroll
                for (int jk = 0; jk < 2; ++jk) {
                    int row = rt * 16 + lr;
                    int ck  = jk * 4 + lg;
                    int idx = w * 2048 + row * 64 + ((ck ^ (row & 7)) << 3);
                    pa[jk] = *(bf16x8*)&Ps[idx];
                }
                #pragma unroll
                for (int dt = 0; dt < 4; ++dt) {
                    #pragma unroll
                    for (int jk = 0; jk < 2; ++jk) {
                        int d   = dt * 16 + lr;
                        int ck  = jk * 4 + lg;
                        int idx = d * 64 + ((ck ^ (d & 7)) << 3);
                        bf16x8 vb = *(bf16x8*)&Vs[idx];
                        O[rt][dt] = __builtin_amdgcn_mfma_f32_16x16x32_bf16(pa[jk], vb, O[rt][dt], 0, 0, 0);
                    }
                }
            }
        }

        #pragma unroll
        for (int rt = 0; rt < 2; ++rt) {
            #pragma unroll
            for (int r = 0; r < 4; ++r) {
                float inv = 1.0f / lrun[rt][r];
                int row = qw + rt * 16 + lg * 4 + r;
                #pragma unroll
                for (int dt = 0; dt < 4; ++dt) {
                    int col = h * DHEAD + dt * 16 + lr;
                    ctxb[(size_t)(b * T_SEQ + row) * CEMB + col] = (short)f2bf(O[rt][dt][r] * inv);
                }
            }
        }
    }
}

// ---------------------------------------------------------------------------
extern "C" void kernel_launch(void* const* d_in, const int* in_sizes, int n_in,
                              void* d_out, int out_size, void* d_ws, size_t ws_size,
                              hipStream_t stream)
{
    const float* x    = (const float*)d_in[0];   // [8192][1024]
    const float* Wqkv = (const float*)d_in[1];   // [1024][3072]
    const float* bqkv = (const float*)d_in[2];   // [3072]
    const float* Wo   = (const float*)d_in[3];   // [1024][1024]
    const float* bo   = (const float*)d_in[4];   // [1024]
    float* out = (float*)d_out;                  // [8192][1024]

    // Workspace (110 MB total; <= 112 MB proven in earlier rounds):
    char* ws = (char*)d_ws;
    float* qk   = (float*)ws;                        // 64 MB [8192][2048] (late)
    short* vbuf = (short*)ws;                        // 16 MB [8192][1024] (early, dead before qk)
    short* Vt   = (short*)(ws + (size_t)(64u << 20)); // 16 MB [B][H][64][T]
    short* ctxb = (short*)(ws + (size_t)(80u << 20)); // 16 MB [8192][1024]
    short* WhiT = (short*)(ws + (size_t)(96u << 20)); // 6 MB [3072][1024]
    short* WloT = (short*)(ws + (size_t)(102u << 20)); // 6 MB
    short* WoT  = (short*)(ws + (size_t)(108u << 20)); // 2 MB [1024][1024]

    // 1) weight transpose+split
    transpose_split_kernel<<<dim3(48, 16), 256, 0, stream>>>(Wqkv, 3 * CEMB, WhiT, WloT);
    transpose_split_kernel<<<dim3(16, 16), 256, 0, stream>>>(Wo, CEMB, WoT, nullptr);

    // 2) V = x @ Wv + bv  (bf16 out, single MFMA)
    gemm_mfma_kernel<1, true, true><<<dim3(8, 64), 256, 0, stream>>>(
        x, nullptr, WhiT + (size_t)2048 * 1024, nullptr, bqkv + 2048, vbuf, CEMB, CEMB);

    // 3) repack V -> Vt
    repack_vt_kernel<<<dim3(32, 16, 4), 256, 0, stream>>>(vbuf, Vt);

    // 4) qk = x @ Wqk + b  (fp32 out, 3-MFMA split; overwrites vbuf region)
    gemm_mfma_kernel<3, true, false><<<dim3(16, 64), 256, 0, stream>>>(
        x, nullptr, WhiT, WloT, bqkv, qk, CEMB, 2048);

    // 5) causal MFMA flash attention -> ctx bf16
    attn_mfma_kernel<<<dim3(512), 256, 0, stream>>>(qk, Vt, ctxb);

    // 6) out = ctx @ Wo + bo  (fp32 out, single MFMA)
    gemm_mfma_kernel<1, false, false><<<dim3(8, 64), 256, 0, stream>>>(
        nullptr, ctxb, WoT, nullptr, bo, out, CEMB, CEMB);
}